// Round 8
// baseline (129.365 us; speedup 1.0000x reference)
//
#include <hip/hip_runtime.h>
#include <math.h>

#define NCH   64
#define IMW   512
#define NPTS  150000
#define TOTAL (2 * NPTS)
#define IMHW  (512 * 512)
#define HID   32
#define NPIX  (2 * IMHW)          // 524288 pixels across both batches
#define NBINS 32768               // fallback sort bins

// =====================  MAIN PATH: dense H + point finish  =====================

// Kernel A: H[pix][32] = b1 + sum_c before[b,c,hw]*W1[c] + sum_c after[b,c,hw]*W1[64+c]
// thread owns 2 consecutive pixels; all loads coalesced.
__global__ __launch_bounds__(256) void dense_h_kernel(
    const float* __restrict__ before,
    const float* __restrict__ after,
    const float* __restrict__ W1,   // [131, 32]
    const float* __restrict__ b1,   // [32]
    float*       __restrict__ H)    // [NPIX, 32]
{
    const long p0 = (long)blockIdx.x * 512 + (long)threadIdx.x * 2;  // even, < NPIX
    const int  b  = (int)(p0 >> 18);
    const int  hw = (int)(p0 & (IMHW - 1));

    const float* bp = before + (long)b * NCH * IMHW + hw;
    const float* ap = after  + (long)b * NCH * IMHW + hw;

    float a0[HID], a1[HID];
    #pragma unroll
    for (int h = 0; h < HID; ++h) { a0[h] = b1[h]; a1[h] = b1[h]; }

    float2 g[16];

    // before: W1 rows 0..63, chunks of 16 channels
    #pragma unroll
    for (int ck = 0; ck < 4; ++ck) {
        #pragma unroll
        for (int j = 0; j < 16; ++j)
            g[j] = *reinterpret_cast<const float2*>(bp + (long)(ck * 16 + j) * IMHW);
        #pragma unroll
        for (int j = 0; j < 16; ++j) {
            const float* wr = W1 + (ck * 16 + j) * HID;
            #pragma unroll
            for (int h = 0; h < HID; ++h) {
                a0[h] = fmaf(g[j].x, wr[h], a0[h]);
                a1[h] = fmaf(g[j].y, wr[h], a1[h]);
            }
        }
    }
    // after: W1 rows 64..127
    #pragma unroll
    for (int ck = 0; ck < 4; ++ck) {
        #pragma unroll
        for (int j = 0; j < 16; ++j)
            g[j] = *reinterpret_cast<const float2*>(ap + (long)(ck * 16 + j) * IMHW);
        #pragma unroll
        for (int j = 0; j < 16; ++j) {
            const float* wr = W1 + (64 + ck * 16 + j) * HID;
            #pragma unroll
            for (int h = 0; h < HID; ++h) {
                a0[h] = fmaf(g[j].x, wr[h], a0[h]);
                a1[h] = fmaf(g[j].y, wr[h], a1[h]);
            }
        }
    }

    // coalesced stores: 128B per pixel row
    float4* o0 = reinterpret_cast<float4*>(H + p0 * HID);
    float4* o1 = reinterpret_cast<float4*>(H + (p0 + 1) * HID);
    #pragma unroll
    for (int q = 0; q < 8; ++q)
        o0[q] = make_float4(a0[q*4+0], a0[q*4+1], a0[q*4+2], a0[q*4+3]);
    #pragma unroll
    for (int q = 0; q < 8; ++q)
        o1[q] = make_float4(a1[q*4+0], a1[q*4+1], a1[q*4+2], a1[q*4+3]);
}

// Kernel B: per point, read its H row (2 cache lines), finish MLP.
__global__ __launch_bounds__(256) void point_kernel(
    const float* __restrict__ H,
    const float* __restrict__ offsets,
    const int*   __restrict__ coords,
    const float* __restrict__ W1,   // rows 128..130 used
    const float* __restrict__ W2,   // [32, 3]
    const float* __restrict__ b2,   // [3]
    float*       __restrict__ out)  // [2, 150000, 3]
{
    const int gid = blockIdx.x * blockDim.x + threadIdx.x;
    if (gid >= TOTAL) return;

    const int  b     = (gid >= NPTS) ? 1 : 0;
    const long pbase = (long)gid * 3;
    const int  y     = coords[pbase + 1];
    const int  x     = coords[pbase + 2];

    const long pix = (long)b * IMHW + (long)y * IMW + x;
    const float4* hp = reinterpret_cast<const float4*>(H + pix * HID);

    float4 hv[8];
    #pragma unroll
    for (int q = 0; q < 8; ++q) hv[q] = hp[q];

    const float o0 = offsets[pbase + 0];
    const float o1 = offsets[pbase + 1];
    const float o2 = offsets[pbase + 2];
    const float* r0 = W1 + 128 * HID;
    const float* r1 = W1 + 129 * HID;
    const float* r2 = W1 + 130 * HID;

    float q0 = b2[0], q1 = b2[1], q2 = b2[2];
    #pragma unroll
    for (int h = 0; h < HID; ++h) {
        float v = reinterpret_cast<const float*>(hv)[h];
        v = fmaf(o2, r2[h], fmaf(o1, r1[h], fmaf(o0, r0[h], v)));
        v = 0.5f * v * (1.0f + erff(v * 0.70710678118654752f));
        q0 = fmaf(v, W2[h * 3 + 0], q0);
        q1 = fmaf(v, W2[h * 3 + 1], q1);
        q2 = fmaf(v, W2[h * 3 + 2], q2);
    }
    out[pbase + 0] = q0;
    out[pbase + 1] = q1;
    out[pbase + 2] = q2;
}

// =====================  FALLBACK: sorted point-gather (R2 structure)  =====================

__global__ __launch_bounds__(256) void hist_kernel(const int* __restrict__ coords,
                                                   int* __restrict__ hist) {
    int gid = blockIdx.x * blockDim.x + threadIdx.x;
    if (gid >= TOTAL) return;
    const int y = coords[gid * 3 + 1];
    const int x = coords[gid * 3 + 2];
    const int b = (gid >= NPTS) ? 1 : 0;
    atomicAdd(&hist[(b << 14) | (y << 5) | (x >> 4)], 1);
}

__global__ __launch_bounds__(1024) void scan_kernel(const int* __restrict__ hist,
                                                    int* __restrict__ binPos) {
    __shared__ int lds[1024];
    const int t = threadIdx.x;
    const int base = t * 32;
    int loc[32];
    int s = 0;
    #pragma unroll
    for (int i = 0; i < 32; ++i) { loc[i] = s; s += hist[base + i]; }
    lds[t] = s;
    __syncthreads();
    for (int d = 1; d < 1024; d <<= 1) {
        int v = lds[t];
        int add = (t >= d) ? lds[t - d] : 0;
        __syncthreads();
        lds[t] = v + add;
        __syncthreads();
    }
    const int excl = lds[t] - s;
    #pragma unroll
    for (int i = 0; i < 32; ++i) binPos[base + i] = excl + loc[i];
}

__global__ __launch_bounds__(256) void scatter_kernel(const int* __restrict__ coords,
                                                      int* __restrict__ binPos,
                                                      int* __restrict__ perm) {
    int gid = blockIdx.x * blockDim.x + threadIdx.x;
    if (gid >= TOTAL) return;
    const int y = coords[gid * 3 + 1];
    const int x = coords[gid * 3 + 2];
    const int b = (gid >= NPTS) ? 1 : 0;
    const int pos = atomicAdd(&binPos[(b << 14) | (y << 5) | (x >> 4)], 1);
    perm[pos] = gid;
}

__global__ __launch_bounds__(256) void ffd_gather_kernel(
    const float* __restrict__ before,
    const float* __restrict__ after,
    const float* __restrict__ offsets,
    const int*   __restrict__ coords,
    const float* __restrict__ W1,
    const float* __restrict__ b1,
    const float* __restrict__ W2,
    const float* __restrict__ b2,
    const int*   __restrict__ perm,
    float*       __restrict__ out)
{
    int gpt = blockIdx.x * blockDim.x + threadIdx.x;
    const bool valid = gpt < TOTAL;
    if (!valid) gpt = TOTAL - 1;

    const int pid = perm ? perm[gpt] : gpt;
    const long pbase = (long)pid * 3;
    const int y = coords[pbase + 1];
    const int x = coords[pbase + 2];
    const int b = (pid >= NPTS) ? 1 : 0;

    const long img_off = (long)b * NCH * IMHW + (long)y * IMW + x;
    const float* bp = before + img_off;
    const float* ap = after  + img_off;

    float acc[HID];
    {
        const float o0 = offsets[pbase + 0];
        const float o1 = offsets[pbase + 1];
        const float o2 = offsets[pbase + 2];
        const float* r0 = W1 + 128 * HID;
        const float* r1 = W1 + 129 * HID;
        const float* r2 = W1 + 130 * HID;
        #pragma unroll
        for (int h = 0; h < HID; ++h)
            acc[h] = fmaf(o2, r2[h], fmaf(o1, r1[h], fmaf(o0, r0[h], b1[h])));
    }

    float g[16];
    for (int cc = 0; cc < NCH; cc += 16) {
        #pragma unroll
        for (int j = 0; j < 16; ++j) g[j] = bp[(long)(cc + j) * IMHW];
        #pragma unroll
        for (int j = 0; j < 16; ++j) {
            const float* wr = W1 + (cc + j) * HID;
            #pragma unroll
            for (int h = 0; h < HID; ++h) acc[h] = fmaf(g[j], wr[h], acc[h]);
        }
    }
    for (int cc = 0; cc < NCH; cc += 16) {
        #pragma unroll
        for (int j = 0; j < 16; ++j) g[j] = ap[(long)(cc + j) * IMHW];
        #pragma unroll
        for (int j = 0; j < 16; ++j) {
            const float* wr = W1 + (64 + cc + j) * HID;
            #pragma unroll
            for (int h = 0; h < HID; ++h) acc[h] = fmaf(g[j], wr[h], acc[h]);
        }
    }

    #pragma unroll
    for (int h = 0; h < HID; ++h) {
        const float xh = acc[h];
        acc[h] = 0.5f * xh * (1.0f + erff(xh * 0.70710678118654752f));
    }
    float q0 = b2[0], q1 = b2[1], q2 = b2[2];
    #pragma unroll
    for (int h = 0; h < HID; ++h) {
        q0 = fmaf(acc[h], W2[h * 3 + 0], q0);
        q1 = fmaf(acc[h], W2[h * 3 + 1], q1);
        q2 = fmaf(acc[h], W2[h * 3 + 2], q2);
    }
    if (valid) {
        out[pbase + 0] = q0;
        out[pbase + 1] = q1;
        out[pbase + 2] = q2;
    }
}

extern "C" void kernel_launch(void* const* d_in, const int* in_sizes, int n_in,
                              void* d_out, int out_size, void* d_ws, size_t ws_size,
                              hipStream_t stream) {
    const float* before  = (const float*)d_in[0];
    const float* after   = (const float*)d_in[1];
    const float* offsets = (const float*)d_in[2];
    const int*   coords  = (const int*)  d_in[3];
    const float* W1      = (const float*)d_in[4];
    const float* b1      = (const float*)d_in[5];
    const float* W2      = (const float*)d_in[6];
    const float* b2      = (const float*)d_in[7];
    float* out = (float*)d_out;

    const int block = 256;

    const size_t needH = (size_t)NPIX * HID * sizeof(float);   // 67 MB

    if (ws_size >= needH) {
        float* H = (float*)d_ws;
        dense_h_kernel<<<NPIX / 512, block, 0, stream>>>(before, after, W1, b1, H);
        point_kernel<<<(TOTAL + block - 1) / block, block, 0, stream>>>(
            H, offsets, coords, W1, W2, b2, out);
        return;
    }

    // fallback: sorted gather (R2)
    const int grid = (TOTAL + block - 1) / block;
    const size_t needS = (size_t)(2 * NBINS + TOTAL) * sizeof(int);
    if (ws_size >= needS) {
        int* hist   = (int*)d_ws;
        int* binPos = hist + NBINS;
        int* perm   = binPos + NBINS;
        hipMemsetAsync(hist, 0, NBINS * sizeof(int), stream);
        hist_kernel<<<grid, block, 0, stream>>>(coords, hist);
        scan_kernel<<<1, 1024, 0, stream>>>(hist, binPos);
        scatter_kernel<<<grid, block, 0, stream>>>(coords, binPos, perm);
        ffd_gather_kernel<<<grid, block, 0, stream>>>(before, after, offsets, coords,
                                                      W1, b1, W2, b2, perm, out);
    } else {
        ffd_gather_kernel<<<grid, block, 0, stream>>>(before, after, offsets, coords,
                                                      W1, b1, W2, b2, nullptr, out);
    }
}

// Round 9
// 123.475 us; speedup vs baseline: 1.0477x; 1.0477x over previous
//
#include <hip/hip_runtime.h>
#include <math.h>

#define NCH   64
#define IMW   512
#define NPTS  150000
#define TOTAL (2 * NPTS)
#define IMHW  (512 * 512)
#define HID   32
#define NPIX  (2 * IMHW)          // 524288 pixels across both batches

// =====================  Kernel A: dense H, TLP-max  =====================
// 1 pixel/thread, 2048 blocks (8/CU -> up to 32 waves/CU).
// Loads: dword per channel, 64 lanes contiguous (256B/inst).
// Stores: LDS-transposed so every global store inst writes dense full lines.

__global__ __launch_bounds__(256) void dense_h_kernel(
    const float* __restrict__ before,
    const float* __restrict__ after,
    const float* __restrict__ W1,   // [131, 32]
    const float* __restrict__ b1,   // [32]
    float*       __restrict__ H)    // [NPIX, 32]
{
    __shared__ float st[HID][129];  // [h][128 px + 1 pad]

    const int  tid = threadIdx.x;
    const long p   = (long)blockIdx.x * 256 + tid;   // < NPIX
    const int  b   = (int)(p >> 18);                 // p / 262144
    const int  hw  = (int)(p & (IMHW - 1));

    const float* bp = before + (long)b * NCH * IMHW + hw;
    const float* ap = after  + (long)b * NCH * IMHW + hw;

    float acc[HID];
    #pragma unroll
    for (int h = 0; h < HID; ++h) acc[h] = b1[h];    // uniform -> scalar bcast

    float g[16];
    // before: W1 rows 0..63
    #pragma unroll
    for (int ck = 0; ck < 4; ++ck) {
        #pragma unroll
        for (int j = 0; j < 16; ++j) g[j] = bp[(long)(ck * 16 + j) * IMHW];
        #pragma unroll
        for (int j = 0; j < 16; ++j) {
            const float* wr = W1 + (ck * 16 + j) * HID;
            #pragma unroll
            for (int h = 0; h < HID; ++h) acc[h] = fmaf(g[j], wr[h], acc[h]);
        }
    }
    // after: W1 rows 64..127
    #pragma unroll
    for (int ck = 0; ck < 4; ++ck) {
        #pragma unroll
        for (int j = 0; j < 16; ++j) g[j] = ap[(long)(ck * 16 + j) * IMHW];
        #pragma unroll
        for (int j = 0; j < 16; ++j) {
            const float* wr = W1 + (64 + ck * 16 + j) * HID;
            #pragma unroll
            for (int h = 0; h < HID; ++h) acc[h] = fmaf(g[j], wr[h], acc[h]);
        }
    }

    // ---- dense stores via LDS transpose, two 128-px phases ----
    float4* Hv = reinterpret_cast<float4*>(H + (long)blockIdx.x * 256 * HID);

    #pragma unroll
    for (int ph = 0; ph < 2; ++ph) {
        if ((tid >> 7) == ph) {
            const int px = tid & 127;
            #pragma unroll
            for (int h = 0; h < HID; ++h) st[h][px] = acc[h];
        }
        __syncthreads();
        // 1024 float4 slots = 128 px * 32 h; consecutive threads ->
        // consecutive 16B -> each wave-store = 4KB dense.
        #pragma unroll
        for (int r = 0; r < 4; ++r) {
            const int s  = r * 256 + tid;   // slot
            const int px = s >> 3;
            const int hq = s & 7;
            Hv[ph * 1024 + s] = make_float4(st[hq * 4 + 0][px],
                                            st[hq * 4 + 1][px],
                                            st[hq * 4 + 2][px],
                                            st[hq * 4 + 3][px]);
        }
        __syncthreads();
    }
}

// =====================  Kernel B: per-point finish  =====================

__global__ __launch_bounds__(256) void point_kernel(
    const float* __restrict__ H,
    const float* __restrict__ offsets,
    const int*   __restrict__ coords,
    const float* __restrict__ W1,   // rows 128..130 used
    const float* __restrict__ W2,   // [32, 3]
    const float* __restrict__ b2,   // [3]
    float*       __restrict__ out)  // [2, 150000, 3]
{
    const int gid = blockIdx.x * blockDim.x + threadIdx.x;
    if (gid >= TOTAL) return;

    const int  b     = (gid >= NPTS) ? 1 : 0;
    const long pbase = (long)gid * 3;
    const int  y     = coords[pbase + 1];
    const int  x     = coords[pbase + 2];

    const long pix = (long)b * IMHW + (long)y * IMW + x;
    const float4* hp = reinterpret_cast<const float4*>(H + pix * HID);

    float4 hv[8];
    #pragma unroll
    for (int q = 0; q < 8; ++q) hv[q] = hp[q];

    const float o0 = offsets[pbase + 0];
    const float o1 = offsets[pbase + 1];
    const float o2 = offsets[pbase + 2];
    const float* r0 = W1 + 128 * HID;
    const float* r1 = W1 + 129 * HID;
    const float* r2 = W1 + 130 * HID;

    float q0 = b2[0], q1 = b2[1], q2 = b2[2];
    #pragma unroll
    for (int h = 0; h < HID; ++h) {
        float v = reinterpret_cast<const float*>(hv)[h];
        v = fmaf(o2, r2[h], fmaf(o1, r1[h], fmaf(o0, r0[h], v)));
        v = 0.5f * v * (1.0f + erff(v * 0.70710678118654752f));
        q0 = fmaf(v, W2[h * 3 + 0], q0);
        q1 = fmaf(v, W2[h * 3 + 1], q1);
        q2 = fmaf(v, W2[h * 3 + 2], q2);
    }
    out[pbase + 0] = q0;
    out[pbase + 1] = q1;
    out[pbase + 2] = q2;
}

// ============  fallback (tiny ws): direct gather, one thread/point  ============

__global__ __launch_bounds__(256) void ffd_gather_kernel(
    const float* __restrict__ before,
    const float* __restrict__ after,
    const float* __restrict__ offsets,
    const int*   __restrict__ coords,
    const float* __restrict__ W1,
    const float* __restrict__ b1,
    const float* __restrict__ W2,
    const float* __restrict__ b2,
    float*       __restrict__ out)
{
    int gid = blockIdx.x * blockDim.x + threadIdx.x;
    if (gid >= TOTAL) return;
    const long pbase = (long)gid * 3;
    const int y = coords[pbase + 1];
    const int x = coords[pbase + 2];
    const int b = (gid >= NPTS) ? 1 : 0;

    const long img_off = (long)b * NCH * IMHW + (long)y * IMW + x;
    const float* bp = before + img_off;
    const float* ap = after  + img_off;

    float acc[HID];
    {
        const float o0 = offsets[pbase + 0];
        const float o1 = offsets[pbase + 1];
        const float o2 = offsets[pbase + 2];
        const float* r0 = W1 + 128 * HID;
        const float* r1 = W1 + 129 * HID;
        const float* r2 = W1 + 130 * HID;
        #pragma unroll
        for (int h = 0; h < HID; ++h)
            acc[h] = fmaf(o2, r2[h], fmaf(o1, r1[h], fmaf(o0, r0[h], b1[h])));
    }

    float g[16];
    for (int cc = 0; cc < NCH; cc += 16) {
        #pragma unroll
        for (int j = 0; j < 16; ++j) g[j] = bp[(long)(cc + j) * IMHW];
        #pragma unroll
        for (int j = 0; j < 16; ++j) {
            const float* wr = W1 + (cc + j) * HID;
            #pragma unroll
            for (int h = 0; h < HID; ++h) acc[h] = fmaf(g[j], wr[h], acc[h]);
        }
    }
    for (int cc = 0; cc < NCH; cc += 16) {
        #pragma unroll
        for (int j = 0; j < 16; ++j) g[j] = ap[(long)(cc + j) * IMHW];
        #pragma unroll
        for (int j = 0; j < 16; ++j) {
            const float* wr = W1 + (64 + cc + j) * HID;
            #pragma unroll
            for (int h = 0; h < HID; ++h) acc[h] = fmaf(g[j], wr[h], acc[h]);
        }
    }

    #pragma unroll
    for (int h = 0; h < HID; ++h) {
        const float xh = acc[h];
        acc[h] = 0.5f * xh * (1.0f + erff(xh * 0.70710678118654752f));
    }
    float q0 = b2[0], q1 = b2[1], q2 = b2[2];
    #pragma unroll
    for (int h = 0; h < HID; ++h) {
        q0 = fmaf(acc[h], W2[h * 3 + 0], q0);
        q1 = fmaf(acc[h], W2[h * 3 + 1], q1);
        q2 = fmaf(acc[h], W2[h * 3 + 2], q2);
    }
    out[pbase + 0] = q0;
    out[pbase + 1] = q1;
    out[pbase + 2] = q2;
}

extern "C" void kernel_launch(void* const* d_in, const int* in_sizes, int n_in,
                              void* d_out, int out_size, void* d_ws, size_t ws_size,
                              hipStream_t stream) {
    const float* before  = (const float*)d_in[0];
    const float* after   = (const float*)d_in[1];
    const float* offsets = (const float*)d_in[2];
    const int*   coords  = (const int*)  d_in[3];
    const float* W1      = (const float*)d_in[4];
    const float* b1      = (const float*)d_in[5];
    const float* W2      = (const float*)d_in[6];
    const float* b2      = (const float*)d_in[7];
    float* out = (float*)d_out;

    const int block = 256;
    const size_t needH = (size_t)NPIX * HID * sizeof(float);   // 67 MB

    if (ws_size >= needH) {
        float* H = (float*)d_ws;
        dense_h_kernel<<<NPIX / 256, block, 0, stream>>>(before, after, W1, b1, H);
        point_kernel<<<(TOTAL + block - 1) / block, block, 0, stream>>>(
            H, offsets, coords, W1, W2, b2, out);
    } else {
        ffd_gather_kernel<<<(TOTAL + block - 1) / block, block, 0, stream>>>(
            before, after, offsets, coords, W1, b1, W2, b2, out);
    }
}